// Round 1
// 3926.878 us; speedup vs baseline: 1.0836x; 1.0836x over previous
//
#include <hip/hip_runtime.h>

#define LSEQ 2048
#define NB 24
#define NH 75
#define G3 225
#define NIN 500
#define OUTW 450

typedef _Float16 h2 __attribute__((ext_vector_type(2)));
typedef _Float16 h8 __attribute__((ext_vector_type(8)));
typedef float f4 __attribute__((ext_vector_type(4)));

__device__ __forceinline__ h2 pkrtz(float a, float b) {
  return __builtin_bit_cast(h2, __builtin_amdgcn_cvt_pkrtz(a, b));
}
__device__ __forceinline__ float dot2(h2 a, h2 b, float c) {
  return __builtin_amdgcn_fdot2(a, b, c, false);
}
// 8-wide half dot: pairs align to dwords, so extracts are free sub-reg refs
__device__ __forceinline__ float dot8(h8 w, h8 x, float c) {
  h2 w0{w[0], w[1]}, w1{w[2], w[3]}, w2{w[4], w[5]}, w3{w[6], w[7]};
  h2 x0{x[0], x[1]}, x1{x[2], x[3]}, x2{x[4], x[5]}, x3{x[6], x[7]};
  c = dot2(w0, x0, c);
  c = dot2(w1, x1, c);
  c = dot2(w2, x2, c);
  c = dot2(w3, x3, c);
  return c;
}
__device__ __forceinline__ h8 ld8f(const float* p, int base, int n) {
  h8 o;
#pragma unroll
  for (int i = 0; i < 8; i += 2) {
    float a = (base + i < n) ? p[base + i] : 0.f;
    float b = (base + i + 1 < n) ? p[base + i + 1] : 0.f;
    h2 t = pkrtz(a, b);
    o[i] = t[0];
    o[i + 1] = t[1];
  }
  return o;
}
__device__ __forceinline__ h8 zero8() {
  h8 v;
#pragma unroll
  for (int i = 0; i < 8; i++) v[i] = (_Float16)0;
  return v;
}
__device__ __forceinline__ float sigm(float x) {
  return __builtin_amdgcn_rcpf(1.f + __builtin_amdgcn_exp2f(-1.4426950408889634f * x));
}
__device__ __forceinline__ float tanh_f(float x) {
  float xx = fminf(x, 15.f);
  float e = __builtin_amdgcn_exp2f(2.8853900817779268f * xx);
  return (e - 1.f) * __builtin_amdgcn_rcpf(e + 1.f);
}

// device-scope relaxed (sc1, no cache-maintenance ops)
__device__ __forceinline__ float ldg_dev(const float* p) {
  return __hip_atomic_load(p, __ATOMIC_RELAXED, __HIP_MEMORY_SCOPE_AGENT);
}
__device__ __forceinline__ void stg_dev(float* p, float v) {
  __hip_atomic_store(p, v, __ATOMIC_RELAXED, __HIP_MEMORY_SCOPE_AGENT);
}
__device__ __forceinline__ int ldflag(const int* p) {
  return __hip_atomic_load(p, __ATOMIC_RELAXED, __HIP_MEMORY_SCOPE_AGENT);
}
__device__ __forceinline__ void stflag(int* p, int v) {
  __hip_atomic_store(p, v, __ATOMIC_RELAXED, __HIP_MEMORY_SCOPE_AGENT);
}

#define PIN4(a, b, c, d) asm("" : "+v"(a), "+v"(b), "+v"(c), "+v"(d))
#define PIN2(a, b) asm("" : "+v"(a), "+v"(b))

// Raw workgroup barrier: does NOT drain vmcnt (that is the whole point).
// LDS producer->consumer ordering needs lgkmcnt(0) on the writer side;
// sched_barrier(0) pins the instruction scheduler on both sides (rule #18).
#define WG_BARRIER()                                     \
  do {                                                   \
    asm volatile("s_waitcnt lgkmcnt(0)" ::: "memory");   \
    __builtin_amdgcn_sched_barrier(0);                   \
    __builtin_amdgcn_s_barrier();                        \
    __builtin_amdgcn_sched_barrier(0);                   \
  } while (0)

// ---------------- init flags ----------------
__global__ void init_flags(int* f) {
  if (threadIdx.x < 144) stflag(&f[threadIdx.x], 0);
}

// ---------------- kernel A: gx GEMM (unchanged, it works) ----------------
__device__ __forceinline__ void load8_guard(float* v, const float* src, int kbase, bool rowvalid) {
  if (rowvalid && (kbase + 8 <= NIN)) {
    f4 t0 = *(const f4*)(src);
    f4 t1 = *(const f4*)(src + 4);
    v[0] = t0[0]; v[1] = t0[1]; v[2] = t0[2]; v[3] = t0[3];
    v[4] = t1[0]; v[5] = t1[1]; v[6] = t1[2]; v[7] = t1[3];
  } else {
#pragma unroll
    for (int i = 0; i < 8; i++) v[i] = (rowvalid && (kbase + i < NIN)) ? src[i] : 0.f;
  }
}
__device__ __forceinline__ void pack8_store(_Float16* dst, const float* v) {
  h2 a = pkrtz(v[0], v[1]);
  h2 b = pkrtz(v[2], v[3]);
  h2 c = pkrtz(v[4], v[5]);
  h2 d = pkrtz(v[6], v[7]);
  h8 o;
  o[0] = a[0]; o[1] = a[1]; o[2] = b[0]; o[3] = b[1];
  o[4] = c[0]; o[5] = c[1]; o[6] = d[0]; o[7] = d[1];
  *(h8*)dst = o;
}

__global__ __launch_bounds__(256) void gemm_gx(const float* __restrict__ x,
                                               const float* __restrict__ w,
                                               const float* __restrict__ bias,
                                               float* __restrict__ out) {
  __shared__ __align__(16) _Float16 xs[64 * 40];
  __shared__ __align__(16) _Float16 wsh[464 * 40];
  const int tid = threadIdx.x;
  const int blk = blockIdx.x;
  const int lane = tid & 63, wid = tid >> 6;
  const int q = lane >> 4, cn = lane & 15;
  const int r = tid >> 2, kq = tid & 3;

  f4 acc[29];
#pragma unroll
  for (int j = 0; j < 29; j++) acc[j] = f4{0.f, 0.f, 0.f, 0.f};

  for (int kc = 0; kc < 16; kc++) {
    const int kbase = kc * 32 + kq * 8;
    {
      const float* src = x + (size_t)(blk * 64 + r) * NIN + kbase;
      float v[8];
      load8_guard(v, src, kbase, true);
      pack8_store(&xs[r * 40 + kq * 8], v);
    }
#pragma unroll
    for (int it = 0; it < 8; it++) {
      int rr = r + it * 64;
      if (rr < 464) {
        const float* src = w + (size_t)rr * NIN + kbase;
        float v[8];
        load8_guard(v, src, kbase, rr < OUTW);
        pack8_store(&wsh[rr * 40 + kq * 8], v);
      }
    }
    __syncthreads();
    h8 a = *(const h8*)&xs[(wid * 16 + cn) * 40 + q * 8];
#pragma unroll
    for (int j = 0; j < 29; j++) {
      h8 bf = *(const h8*)&wsh[(j * 16 + cn) * 40 + q * 8];
      acc[j] = __builtin_amdgcn_mfma_f32_16x16x32_f16(a, bf, acc[j], 0, 0, 0);
    }
    __syncthreads();
  }
#pragma unroll
  for (int j = 0; j < 29; j++) {
    int n = j * 16 + cn;
    float bv = (n < OUTW) ? bias[n] : 0.f;
#pragma unroll
    for (int rr = 0; rr < 4; rr++) {
      float val = acc[j][rr] + bv;
      float partner = __shfl_xor(val, 1, 64);
      if (((lane & 1) == 0) && n < OUTW) {
        h2 pk = pkrtz(val, partner);
        int mg = blk * 64 + wid * 16 + q * 4 + rr;
        out[(size_t)mg * OUTW + G3 + (n >> 1)] = __builtin_bit_cast(float, pk);
      }
    }
  }
}

// ---------------- kernel B: persistent GRU scan ----------------
// 144 WGs = cell c (0..5) x batch b (0..23), bi = c*24+b.
// Lane map (NEW): tid 0..112 gate lanes (rows 2t, 2t+1);
//   h-update lanes = tid 128..191 (j=0..63) + tid 113..123 (j=64..74), so the
//   sync wave (wave 3) carries ONLY prefetch loads in its vmcnt counter and the
//   h waves carry ONLY h-stores -> counted s_waitcnt stays exact per wave.
//   Sync lanes: tid 208..237. tid 203..207 zero-pad h16.
// NEW sync scheme (replaces __syncthreads vmcnt(0) drains):
//  - raw s_barrier + lgkmcnt(0) only (WG_BARRIER); vmem stays in flight.
//  - sync wave double-buffers prefetch (PA/PB): loads issued at step t are
//    written to the LDS ring at t+4 -> 4 full steps (~5000cy) in flight.
//    In-step order store-old -> poll -> load-new so implicit waits only ever
//    hit 4-step-old loads (~0 cycles).
//  - producers: after each 4-store batch, h waves do s_waitcnt vmcnt(4)
//    (vmcnt retires in issue order => all OLDER batches globally visible),
//    then flag F = t-4 is published after the following barrier.
//    Consumer lag deepens by 4 steps; protocol semantics unchanged.
__global__ __launch_bounds__(256, 1) __attribute__((amdgpu_waves_per_eu(1)))
void scan_gru(const float* __restrict__ h0,
              const float* __restrict__ w_hh0, const float* __restrict__ b_hh0,
              const float* __restrict__ w_ih12, const float* __restrict__ w_hh12,
              const float* __restrict__ b_ih12, const float* __restrict__ b_hh12,
              float* __restrict__ out, int* flags) {
  __shared__ __align__(16) float A_s[232], B_s[232];
  __shared__ __align__(16) _Float16 h16[80];
  __shared__ __align__(16) _Float16 xr[16][152];

  const int bi = blockIdx.x;
  if (bi >= 144) return;
  const int tid = threadIdx.x;
  const int c = bi / NB, b = bi % NB;
  const int l = c >> 1, d = c & 1;
  const int ci = (l - 1) * 2 + d;   // index into *_12 arrays (l>=1)
  const int u0 = (l - 1) * 2;       // upstream cell pair

  const int r0 = tid * 2;
  const int r0c = (r0 < G3) ? r0 : G3 - 1;
  const int r1c = (r0 + 1 < G3) ? r0 + 1 : G3 - 1;
  const bool isgate = (tid < 113);
  const bool ish = (tid >= 128 && tid < 192) || (tid >= 113 && tid < 124);
  const int hj = (tid >= 128) ? (tid - 128) : (tid - 49);  // 113..123 -> 64..74
  const int s = tid - 208;
  const bool issync = (s >= 0) && (s < 30) && (l >= 1);

#define SYNC_LOAD20(Pr, base)                                                            \
  do {                                                                                   \
    _Pragma("unroll") for (int i = 0; i < 20; i++) {                                     \
      int qq = s * 20 + i;                                                               \
      int tt = (base) + qq / 150;                                                        \
      int rem = qq % 150;                                                                \
      Pr[i >> 2][i & 3] = ldg_dev(&out[((size_t)tt * NB + b) * OUTW + u0 * NH + rem]);   \
    }                                                                                    \
  } while (0)

#define SYNC_STORE20(Pr, base)                                                           \
  do {                                                                                   \
    _Pragma("unroll") for (int i = 0; i < 20; i++) {                                     \
      int qq = s * 20 + i;                                                               \
      int tt = (base) + qq / 150;                                                        \
      int rem = qq % 150;                                                                \
      xr[tt & 15][rem] = (_Float16)Pr[i >> 2][i & 3];                                    \
    }                                                                                    \
  } while (0)

  // ---- weights, 2 rows per gate lane, named h8 regs ----
  h8 Wa0 = zero8(), Wa1 = zero8(), Wa2 = zero8(), Wa3 = zero8(), Wa4 = zero8();
  h8 Wa5 = zero8(), Wa6 = zero8(), Wa7 = zero8(), Wa8 = zero8(), Wa9 = zero8();
  h8 Wb0 = zero8(), Wb1 = zero8(), Wb2 = zero8(), Wb3 = zero8(), Wb4 = zero8();
  h8 Wb5 = zero8(), Wb6 = zero8(), Wb7 = zero8(), Wb8 = zero8(), Wb9 = zero8();
  h8 Ua0 = zero8(), Ua1 = zero8(), Ua2 = zero8(), Ua3 = zero8(), Ua4 = zero8();
  h8 Ua5 = zero8(), Ua6 = zero8(), Ua7 = zero8(), Ua8 = zero8(), Ua9 = zero8();
  h8 Ua10 = zero8(), Ua11 = zero8(), Ua12 = zero8(), Ua13 = zero8(), Ua14 = zero8();
  h8 Ua15 = zero8(), Ua16 = zero8(), Ua17 = zero8(), Ua18 = zero8();
  h8 Ub0 = zero8(), Ub1 = zero8(), Ub2 = zero8(), Ub3 = zero8(), Ub4 = zero8();
  h8 Ub5 = zero8(), Ub6 = zero8(), Ub7 = zero8(), Ub8 = zero8(), Ub9 = zero8();
  h8 Ub10 = zero8(), Ub11 = zero8(), Ub12 = zero8(), Ub13 = zero8(), Ub14 = zero8();
  h8 Ub15 = zero8(), Ub16 = zero8(), Ub17 = zero8(), Ub18 = zero8();
  float bhha = 0.f, bhhb = 0.f, biha = 0.f, bihb = 0.f;

  if (isgate) {
    const float* wA = (l == 0) ? w_hh0 + (size_t)(d * G3 + r0c) * NH
                               : w_hh12 + (size_t)(ci * G3 + r0c) * NH;
    const float* wB = (l == 0) ? w_hh0 + (size_t)(d * G3 + r1c) * NH
                               : w_hh12 + (size_t)(ci * G3 + r1c) * NH;
    Wa0 = ld8f(wA, 0, NH);  Wa1 = ld8f(wA, 8, NH);  Wa2 = ld8f(wA, 16, NH);
    Wa3 = ld8f(wA, 24, NH); Wa4 = ld8f(wA, 32, NH); Wa5 = ld8f(wA, 40, NH);
    Wa6 = ld8f(wA, 48, NH); Wa7 = ld8f(wA, 56, NH); Wa8 = ld8f(wA, 64, NH);
    Wa9 = ld8f(wA, 72, NH);
    Wb0 = ld8f(wB, 0, NH);  Wb1 = ld8f(wB, 8, NH);  Wb2 = ld8f(wB, 16, NH);
    Wb3 = ld8f(wB, 24, NH); Wb4 = ld8f(wB, 32, NH); Wb5 = ld8f(wB, 40, NH);
    Wb6 = ld8f(wB, 48, NH); Wb7 = ld8f(wB, 56, NH); Wb8 = ld8f(wB, 64, NH);
    Wb9 = ld8f(wB, 72, NH);
    bhha = (l == 0) ? b_hh0[d * G3 + r0c] : b_hh12[ci * G3 + r0c];
    bhhb = (l == 0) ? b_hh0[d * G3 + r1c] : b_hh12[ci * G3 + r1c];
    if (l > 0) {
      const float* uA = w_ih12 + (size_t)(ci * G3 + r0c) * (2 * NH);
      const float* uB = w_ih12 + (size_t)(ci * G3 + r1c) * (2 * NH);
      Ua0 = ld8f(uA, 0, 150);   Ua1 = ld8f(uA, 8, 150);   Ua2 = ld8f(uA, 16, 150);
      Ua3 = ld8f(uA, 24, 150);  Ua4 = ld8f(uA, 32, 150);  Ua5 = ld8f(uA, 40, 150);
      Ua6 = ld8f(uA, 48, 150);  Ua7 = ld8f(uA, 56, 150);  Ua8 = ld8f(uA, 64, 150);
      Ua9 = ld8f(uA, 72, 150);  Ua10 = ld8f(uA, 80, 150); Ua11 = ld8f(uA, 88, 150);
      Ua12 = ld8f(uA, 96, 150); Ua13 = ld8f(uA, 104, 150); Ua14 = ld8f(uA, 112, 150);
      Ua15 = ld8f(uA, 120, 150); Ua16 = ld8f(uA, 128, 150); Ua17 = ld8f(uA, 136, 150);
      Ua18 = ld8f(uA, 144, 150);
      Ub0 = ld8f(uB, 0, 150);   Ub1 = ld8f(uB, 8, 150);   Ub2 = ld8f(uB, 16, 150);
      Ub3 = ld8f(uB, 24, 150);  Ub4 = ld8f(uB, 32, 150);  Ub5 = ld8f(uB, 40, 150);
      Ub6 = ld8f(uB, 48, 150);  Ub7 = ld8f(uB, 56, 150);  Ub8 = ld8f(uB, 64, 150);
      Ub9 = ld8f(uB, 72, 150);  Ub10 = ld8f(uB, 80, 150); Ub11 = ld8f(uB, 88, 150);
      Ub12 = ld8f(uB, 96, 150); Ub13 = ld8f(uB, 104, 150); Ub14 = ld8f(uB, 112, 150);
      Ub15 = ld8f(uB, 120, 150); Ub16 = ld8f(uB, 128, 150); Ub17 = ld8f(uB, 136, 150);
      Ub18 = ld8f(uB, 144, 150);
      biha = b_ih12[ci * G3 + r0c];
      bihb = b_ih12[ci * G3 + r1c];
    }
  }

  float hreg = 0.f, hh0 = 0.f, hh1 = 0.f, hh2 = 0.f;
  if (ish) {
    hreg = h0[(size_t)(c * NB + b) * NH + hj];
    h16[hj] = (_Float16)hreg;
  }
  if (tid >= 203 && tid < 208) h16[NH + (tid - 203)] = (_Float16)0;
  if (tid < 16) { xr[tid][150] = (_Float16)0; xr[tid][151] = (_Float16)0; }

  // sync-lane double-buffer prefetch regs (const-indexed only)
  f4 PA[5], PB[5];
#pragma unroll
  for (int i = 0; i < 5; i++) { PA[i] = f4{0.f, 0.f, 0.f, 0.f}; PB[i] = f4{0.f, 0.f, 0.f, 0.f}; }

  // prologue: fill ring times 0..7 directly, preload PB with times 8..11,
  // then pre-verify flag>=16 (covers t=0's PA load of times 12..15).
  if (issync) {
    const int* f0 = &flags[u0 * NB + b];
    const int* f1 = &flags[(u0 + 1) * NB + b];
    for (int p = 0; p < 2; p++) {
      while (ldflag(f0) < 4 * p + 4 || ldflag(f1) < 4 * p + 4) {}
#pragma unroll
      for (int i = 0; i < 20; i++) {
        int q = s * 20 + i;
        int tt = 4 * p + q / 150;
        int rem = q % 150;
        float v = ldg_dev(&out[((size_t)tt * NB + b) * OUTW + u0 * NH + rem]);
        xr[tt & 15][rem] = (_Float16)v;
      }
    }
    while (ldflag(f0) < 12 || ldflag(f1) < 12) {}
    SYNC_LOAD20(PB, 8);
    while (ldflag(f0) < 16 || ldflag(f1) < 16) {}
  }

  // prologue: layer-0 gx(0)
  float gxc0 = 0.f, gxc1 = 0.f, gxn0 = 0.f, gxn1 = 0.f;
  if (l == 0 && tid < 113) {
    int n0 = d * G3 + r0;
    const float* row = out + (size_t)b * OUTW + G3;
    float s0 = row[n0 >> 1];
    float s1 = (d == 1) ? row[(n0 + 1) >> 1] : s0;
    h2 p0 = __builtin_bit_cast(h2, s0);
    h2 p1 = __builtin_bit_cast(h2, s1);
    gxc0 = (n0 & 1) ? (float)p0[1] : (float)p0[0];
    gxc1 = ((n0 + 1) & 1) ? (float)p1[1] : (float)p1[0];
  }
  __syncthreads();  // heavy barrier once, entering steady state

  for (int t = 0; t < LSEQ; t++) {
    // ================= P1 =================
    if (isgate) {
      // keep weights register-resident (defeat remat/reload)
      PIN4(Wa0, Wa1, Wa2, Wa3); PIN4(Wa4, Wa5, Wa6, Wa7); PIN2(Wa8, Wa9);
      PIN4(Wb0, Wb1, Wb2, Wb3); PIN4(Wb4, Wb5, Wb6, Wb7); PIN2(Wb8, Wb9);
      if (l > 0) {
        PIN4(Ua0, Ua1, Ua2, Ua3); PIN4(Ua4, Ua5, Ua6, Ua7); PIN4(Ua8, Ua9, Ua10, Ua11);
        PIN4(Ua12, Ua13, Ua14, Ua15); PIN2(Ua16, Ua17); asm("" : "+v"(Ua18));
        PIN4(Ub0, Ub1, Ub2, Ub3); PIN4(Ub4, Ub5, Ub6, Ub7); PIN4(Ub8, Ub9, Ub10, Ub11);
        PIN4(Ub12, Ub13, Ub14, Ub15); PIN2(Ub16, Ub17); asm("" : "+v"(Ub18));
      }
      const h8* hv = (const h8*)h16;
      h8 H0 = hv[0], H1 = hv[1], H2 = hv[2], H3 = hv[3], H4 = hv[4];
      h8 H5 = hv[5], H6 = hv[6], H7 = hv[7], H8 = hv[8], H9 = hv[9];
      float b0a = dot8(Wa0, H0, bhha), b0b = dot8(Wa1, H1, 0.f);
      b0a = dot8(Wa2, H2, b0a); b0b = dot8(Wa3, H3, b0b);
      b0a = dot8(Wa4, H4, b0a); b0b = dot8(Wa5, H5, b0b);
      b0a = dot8(Wa6, H6, b0a); b0b = dot8(Wa7, H7, b0b);
      b0a = dot8(Wa8, H8, b0a); b0b = dot8(Wa9, H9, b0b);
      float b1a = dot8(Wb0, H0, bhhb), b1b = dot8(Wb1, H1, 0.f);
      b1a = dot8(Wb2, H2, b1a); b1b = dot8(Wb3, H3, b1b);
      b1a = dot8(Wb4, H4, b1a); b1b = dot8(Wb5, H5, b1b);
      b1a = dot8(Wb6, H6, b1a); b1b = dot8(Wb7, H7, b1b);
      b1a = dot8(Wb8, H8, b1a); b1b = dot8(Wb9, H9, b1b);
      float accB0 = b0a + b0b, accB1 = b1a + b1b;
      float accA0, accA1;
      if (l == 0) {
        accA0 = gxc0;
        accA1 = gxc1;
      } else {
        const h8* xv = (const h8*)xr[t & 15];
        h8 X0 = xv[0], X1 = xv[1], X2 = xv[2], X3 = xv[3], X4 = xv[4];
        h8 X5 = xv[5], X6 = xv[6], X7 = xv[7], X8 = xv[8], X9 = xv[9];
        h8 X10 = xv[10], X11 = xv[11], X12 = xv[12], X13 = xv[13], X14 = xv[14];
        h8 X15 = xv[15], X16 = xv[16], X17 = xv[17], X18 = xv[18];
        float a0a = dot8(Ua0, X0, biha), a0b = dot8(Ua1, X1, 0.f);
        a0a = dot8(Ua2, X2, a0a);   a0b = dot8(Ua3, X3, a0b);
        a0a = dot8(Ua4, X4, a0a);   a0b = dot8(Ua5, X5, a0b);
        a0a = dot8(Ua6, X6, a0a);   a0b = dot8(Ua7, X7, a0b);
        a0a = dot8(Ua8, X8, a0a);   a0b = dot8(Ua9, X9, a0b);
        a0a = dot8(Ua10, X10, a0a); a0b = dot8(Ua11, X11, a0b);
        a0a = dot8(Ua12, X12, a0a); a0b = dot8(Ua13, X13, a0b);
        a0a = dot8(Ua14, X14, a0a); a0b = dot8(Ua15, X15, a0b);
        a0a = dot8(Ua16, X16, a0a); a0b = dot8(Ua17, X17, a0b);
        a0a = dot8(Ua18, X18, a0a);
        float a1a = dot8(Ub0, X0, bihb), a1b = dot8(Ub1, X1, 0.f);
        a1a = dot8(Ub2, X2, a1a);   a1b = dot8(Ub3, X3, a1b);
        a1a = dot8(Ub4, X4, a1a);   a1b = dot8(Ub5, X5, a1b);
        a1a = dot8(Ub6, X6, a1a);   a1b = dot8(Ub7, X7, a1b);
        a1a = dot8(Ub8, X8, a1a);   a1b = dot8(Ub9, X9, a1b);
        a1a = dot8(Ub10, X10, a1a); a1b = dot8(Ub11, X11, a1b);
        a1a = dot8(Ub12, X12, a1a); a1b = dot8(Ub13, X13, a1b);
        a1a = dot8(Ub14, X14, a1a); a1b = dot8(Ub15, X15, a1b);
        a1a = dot8(Ub16, X16, a1a); a1b = dot8(Ub17, X17, a1b);
        a1a = dot8(Ub18, X18, a1a);
        accA0 = a0a + a0b;
        accA1 = a1a + a1b;
      }
      if (tid < 112) {
        *(float2*)(A_s + r0) = make_float2(accA0, accA1);
        *(float2*)(B_s + r0) = make_float2(accB0, accB1);
      } else if (tid == 112) {
        A_s[224] = accA0;
        B_s[224] = accB0;
      }
      // layer-0: prefetch gx(t+1); with raw barriers it now stays in flight
      // for a full step instead of being drained at barrier1.
      if (l == 0 && tid < 113 && (t + 1 < LSEQ)) {
        int n0 = d * G3 + r0;
        const float* row = out + ((size_t)(t + 1) * NB + b) * OUTW + G3;
        float s0 = row[n0 >> 1];
        float s1 = (d == 1) ? row[(n0 + 1) >> 1] : s0;
        h2 p0 = __builtin_bit_cast(h2, s0);
        h2 p1 = __builtin_bit_cast(h2, s1);
        gxn0 = (n0 & 1) ? (float)p0[1] : (float)p0[0];
        gxn1 = ((n0 + 1) & 1) ? (float)p1[1] : (float)p1[0];
      }
    }
    if (issync && (t & 3) == 0) {
      // (1) retire the 4-step-old prefetch into the ring (times t+8..t+11);
      //     the implicit vmcnt wait here targets loads issued ~4 steps ago -> ~free.
      if (t + 8 < LSEQ) {
        if (t & 4) SYNC_STORE20(PA, t + 8); else SYNC_STORE20(PB, t + 8);
      }
      // (2) pipelined flag check for the batch loaded at t+4 (times t+16..t+19).
      if (t + 20 <= LSEQ) {
        const int* f0 = &flags[u0 * NB + b];
        const int* f1 = &flags[(u0 + 1) * NB + b];
        int need = t + 20;
        while (ldflag(f0) < need || ldflag(f1) < need) {}
      }
      // (3) issue fresh prefetch (times t+12..t+15); nothing consumes these
      //     until t+4, so they fly across the next 8 raw barriers.
      if (t + 12 < LSEQ) {
        if (t & 4) SYNC_LOAD20(PB, t + 12); else SYNC_LOAD20(PA, t + 12);
      }
    }
    // publish F = t-4: h-stores for times <= t-5 were vmcnt(4)-confirmed at
    // step t-1 P2, and barrier2 of t-1 ordered that before this store.
    if (tid == 0 && c < 4 && (t & 3) == 0 && t >= 8) stflag(&flags[c * NB + b], t - 4);
    WG_BARRIER();  // barrier1 (lgkm-only; vmem stays in flight)

    // ================= P2 =================
    if (ish) {
      float rg = sigm(A_s[hj] + B_s[hj]);
      float zg = sigm(A_s[NH + hj] + B_s[NH + hj]);
      float ng = tanh_f(A_s[2 * NH + hj] + rg * B_s[2 * NH + hj]);
      float hn = (1.f - zg) * ng + zg * hreg;
      hreg = hn;
      h16[hj] = (_Float16)hn;
      hh0 = ((t & 3) == 0) ? hn : hh0;
      hh1 = ((t & 3) == 1) ? hn : hh1;
      hh2 = ((t & 3) == 2) ? hn : hh2;
      if ((t & 3) == 3) {
        float* base = out + (size_t)(t - 3) * NB * OUTW + (size_t)b * OUTW + c * NH + hj;
        stg_dev(base, hh0);
        stg_dev(base + (size_t)NB * OUTW, hh1);
        stg_dev(base + 2 * (size_t)NB * OUTW, hh2);
        stg_dev(base + 3 * (size_t)NB * OUTW, hn);
        // counted drain: all store batches OLDER than these 4 are now
        // globally visible (vmcnt retires in issue order). ~0 actual wait.
        asm volatile("s_waitcnt vmcnt(4)" ::: "memory");
      }
    }
    WG_BARRIER();  // barrier2 (orders h16/A_s reuse and the vmcnt(4) above)
    gxc0 = gxn0;
    gxc1 = gxn1;
  }
  __syncthreads();  // full drain (incl. last h-store batch) before final publish
  if (tid == 0 && c < 4) stflag(&flags[c * NB + b], LSEQ);
}

extern "C" void kernel_launch(void* const* d_in, const int* in_sizes, int n_in,
                              void* d_out, int out_size, void* d_ws, size_t ws_size,
                              hipStream_t stream) {
  const float* x      = (const float*)d_in[0];
  const float* h0     = (const float*)d_in[1];
  const float* w_ih0  = (const float*)d_in[2];
  const float* w_hh0  = (const float*)d_in[3];
  const float* b_ih0  = (const float*)d_in[4];
  const float* b_hh0  = (const float*)d_in[5];
  const float* w_ih12 = (const float*)d_in[6];
  const float* w_hh12 = (const float*)d_in[7];
  const float* b_ih12 = (const float*)d_in[8];
  const float* b_hh12 = (const float*)d_in[9];
  float* out = (float*)d_out;
  int* flags = (int*)d_ws;

  hipLaunchKernelGGL(init_flags, dim3(1), dim3(256), 0, stream, flags);
  hipLaunchKernelGGL(gemm_gx, dim3(768), dim3(256), 0, stream, x, w_ih0, b_ih0, out);
  hipLaunchKernelGGL(scan_gru, dim3(144), dim3(256), 0, stream,
                     h0, w_hh0, b_hh0, w_ih12, w_hh12, b_ih12, b_hh12, out, flags);
}

// Round 4
// 3193.586 us; speedup vs baseline: 1.3324x; 1.2296x over previous
//
#include <hip/hip_runtime.h>

#define LSEQ 2048
#define NB 24
#define NH 75
#define G3 225
#define NIN 500
#define OUTW 450

typedef _Float16 h2 __attribute__((ext_vector_type(2)));
typedef _Float16 h8 __attribute__((ext_vector_type(8)));
typedef float f4 __attribute__((ext_vector_type(4)));

__device__ __forceinline__ h2 pkrtz(float a, float b) {
  return __builtin_bit_cast(h2, __builtin_amdgcn_cvt_pkrtz(a, b));
}
__device__ __forceinline__ float dot2(h2 a, h2 b, float c) {
  return __builtin_amdgcn_fdot2(a, b, c, false);
}
// 8-wide half dot: pairs align to dwords, so extracts are free sub-reg refs
__device__ __forceinline__ float dot8(h8 w, h8 x, float c) {
  h2 w0{w[0], w[1]}, w1{w[2], w[3]}, w2{w[4], w[5]}, w3{w[6], w[7]};
  h2 x0{x[0], x[1]}, x1{x[2], x[3]}, x2{x[4], x[5]}, x3{x[6], x[7]};
  c = dot2(w0, x0, c);
  c = dot2(w1, x1, c);
  c = dot2(w2, x2, c);
  c = dot2(w3, x3, c);
  return c;
}
__device__ __forceinline__ h8 ld8f(const float* p, int base, int n) {
  h8 o;
#pragma unroll
  for (int i = 0; i < 8; i += 2) {
    float a = (base + i < n) ? p[base + i] : 0.f;
    float b = (base + i + 1 < n) ? p[base + i + 1] : 0.f;
    h2 t = pkrtz(a, b);
    o[i] = t[0];
    o[i + 1] = t[1];
  }
  return o;
}
__device__ __forceinline__ h8 zero8() {
  h8 v;
#pragma unroll
  for (int i = 0; i < 8; i++) v[i] = (_Float16)0;
  return v;
}
__device__ __forceinline__ float sigm(float x) {
  return __builtin_amdgcn_rcpf(1.f + __builtin_amdgcn_exp2f(-1.4426950408889634f * x));
}
__device__ __forceinline__ float tanh_f(float x) {
  float xx = fminf(x, 15.f);
  float e = __builtin_amdgcn_exp2f(2.8853900817779268f * xx);
  return (e - 1.f) * __builtin_amdgcn_rcpf(e + 1.f);
}

// device-scope relaxed (sc1, no cache-maintenance ops)
__device__ __forceinline__ float ldg_dev(const float* p) {
  return __hip_atomic_load(p, __ATOMIC_RELAXED, __HIP_MEMORY_SCOPE_AGENT);
}
__device__ __forceinline__ void stg_dev(float* p, float v) {
  __hip_atomic_store(p, v, __ATOMIC_RELAXED, __HIP_MEMORY_SCOPE_AGENT);
}
__device__ __forceinline__ int ldflag(const int* p) {
  return __hip_atomic_load(p, __ATOMIC_RELAXED, __HIP_MEMORY_SCOPE_AGENT);
}
__device__ __forceinline__ void stflag(int* p, int v) {
  __hip_atomic_store(p, v, __ATOMIC_RELAXED, __HIP_MEMORY_SCOPE_AGENT);
}

#define PIN4(a, b, c, d) asm("" : "+v"(a), "+v"(b), "+v"(c), "+v"(d))
#define PIN2(a, b) asm("" : "+v"(a), "+v"(b))

// Raw workgroup barrier: does NOT drain vmcnt.
// LDS producer->consumer ordering needs lgkmcnt(0) on the writer side;
// sched_barrier(0) pins the instruction scheduler on both sides (rule #18).
#define WG_BARRIER()                                     \
  do {                                                   \
    asm volatile("s_waitcnt lgkmcnt(0)" ::: "memory");   \
    __builtin_amdgcn_sched_barrier(0);                   \
    __builtin_amdgcn_s_barrier();                        \
    __builtin_amdgcn_sched_barrier(0);                   \
  } while (0)

// ---------------- init flags ----------------
__global__ void init_flags(int* f) {
  if (threadIdx.x < 144) stflag(&f[threadIdx.x], 0);
}

// ---------------- kernel A: gx GEMM (unchanged, it works) ----------------
__device__ __forceinline__ void load8_guard(float* v, const float* src, int kbase, bool rowvalid) {
  if (rowvalid && (kbase + 8 <= NIN)) {
    f4 t0 = *(const f4*)(src);
    f4 t1 = *(const f4*)(src + 4);
    v[0] = t0[0]; v[1] = t0[1]; v[2] = t0[2]; v[3] = t0[3];
    v[4] = t1[0]; v[5] = t1[1]; v[6] = t1[2]; v[7] = t1[3];
  } else {
#pragma unroll
    for (int i = 0; i < 8; i++) v[i] = (rowvalid && (kbase + i < NIN)) ? src[i] : 0.f;
  }
}
__device__ __forceinline__ void pack8_store(_Float16* dst, const float* v) {
  h2 a = pkrtz(v[0], v[1]);
  h2 b = pkrtz(v[2], v[3]);
  h2 c = pkrtz(v[4], v[5]);
  h2 d = pkrtz(v[6], v[7]);
  h8 o;
  o[0] = a[0]; o[1] = a[1]; o[2] = b[0]; o[3] = b[1];
  o[4] = c[0]; o[5] = c[1]; o[6] = d[0]; o[7] = d[1];
  *(h8*)dst = o;
}

__global__ __launch_bounds__(256) void gemm_gx(const float* __restrict__ x,
                                               const float* __restrict__ w,
                                               const float* __restrict__ bias,
                                               float* __restrict__ out) {
  __shared__ __align__(16) _Float16 xs[64 * 40];
  __shared__ __align__(16) _Float16 wsh[464 * 40];
  const int tid = threadIdx.x;
  const int blk = blockIdx.x;
  const int lane = tid & 63, wid = tid >> 6;
  const int q = lane >> 4, cn = lane & 15;
  const int r = tid >> 2, kq = tid & 3;

  f4 acc[29];
#pragma unroll
  for (int j = 0; j < 29; j++) acc[j] = f4{0.f, 0.f, 0.f, 0.f};

  for (int kc = 0; kc < 16; kc++) {
    const int kbase = kc * 32 + kq * 8;
    {
      const float* src = x + (size_t)(blk * 64 + r) * NIN + kbase;
      float v[8];
      load8_guard(v, src, kbase, true);
      pack8_store(&xs[r * 40 + kq * 8], v);
    }
#pragma unroll
    for (int it = 0; it < 8; it++) {
      int rr = r + it * 64;
      if (rr < 464) {
        const float* src = w + (size_t)rr * NIN + kbase;
        float v[8];
        load8_guard(v, src, kbase, rr < OUTW);
        pack8_store(&wsh[rr * 40 + kq * 8], v);
      }
    }
    __syncthreads();
    h8 a = *(const h8*)&xs[(wid * 16 + cn) * 40 + q * 8];
#pragma unroll
    for (int j = 0; j < 29; j++) {
      h8 bf = *(const h8*)&wsh[(j * 16 + cn) * 40 + q * 8];
      acc[j] = __builtin_amdgcn_mfma_f32_16x16x32_f16(a, bf, acc[j], 0, 0, 0);
    }
    __syncthreads();
  }
#pragma unroll
  for (int j = 0; j < 29; j++) {
    int n = j * 16 + cn;
    float bv = (n < OUTW) ? bias[n] : 0.f;
#pragma unroll
    for (int rr = 0; rr < 4; rr++) {
      float val = acc[j][rr] + bv;
      float partner = __shfl_xor(val, 1, 64);
      if (((lane & 1) == 0) && n < OUTW) {
        h2 pk = pkrtz(val, partner);
        int mg = blk * 64 + wid * 16 + q * 4 + rr;
        out[(size_t)mg * OUTW + G3 + (n >> 1)] = __builtin_bit_cast(float, pk);
      }
    }
  }
}

// ---------------- kernel B: persistent GRU scan ----------------
// 144 WGs = cell c (0..5) x batch b (0..23), bi = c*24+b.
// Lane map: tid 0..224 gate lanes, ONE row each (row = tid) -> dot issue
//   spread over all 4 waves (halves per-wave VALU issue vs 2-rows/lane).
//   h-update lanes = tid 0..74 (hj = tid), reusing gate lanes in P2.
//   Sync lanes: tid 225..254 (wave 3). tid 225..229 zero-pad h16 at init.
// Sync scheme: raw s_barrier + lgkmcnt-only (WG_BARRIER); vmem in flight.
//  - sync wave double-buffers prefetch (PA/PB), 4 steps in flight.
//  - speculative flag reads: flag values loaded one step early into regs;
//    the (t&3)==0 check compares registers (no IC round-trip on the barrier
//    path); spin-reload only on miss (transients / catch-up).
//  - producers: after each 4-store batch, s_waitcnt vmcnt(4) -> all OLDER
//    batches globally visible; flag F = t-4 published next publish slot.
//  - l0 gx: raw dword kept loop-carried; extract at consumption, load after
//    -> full-step in-flight window, and it is retired before the vmcnt(4).
__global__ __launch_bounds__(256, 1) __attribute__((amdgpu_waves_per_eu(1)))
void scan_gru(const float* __restrict__ h0,
              const float* __restrict__ w_hh0, const float* __restrict__ b_hh0,
              const float* __restrict__ w_ih12, const float* __restrict__ w_hh12,
              const float* __restrict__ b_ih12, const float* __restrict__ b_hh12,
              float* __restrict__ out, int* flags) {
  __shared__ __align__(16) float A_s[232], B_s[232];
  __shared__ __align__(16) _Float16 h16[80];
  __shared__ __align__(16) _Float16 xr[16][152];

  const int bi = blockIdx.x;
  if (bi >= 144) return;
  const int tid = threadIdx.x;
  const int c = bi / NB, b = bi % NB;
  const int l = c >> 1, d = c & 1;
  const int ci = (l - 1) * 2 + d;   // index into *_12 arrays (l>=1)
  const int u0 = (l - 1) * 2;       // upstream cell pair

  const bool isgate = (tid < G3);   // one row per lane: row = tid
  const bool ish = (tid < NH);      // hj = tid
  const int hj = tid;
  const int s = tid - 225;
  const bool issync = (s >= 0) && (s < 30) && (l >= 1);

#define SYNC_LOAD20(Pr, base)                                                            \
  do {                                                                                   \
    _Pragma("unroll") for (int i = 0; i < 20; i++) {                                     \
      int qq = s * 20 + i;                                                               \
      int tt = (base) + qq / 150;                                                        \
      int rem = qq % 150;                                                                \
      Pr[i >> 2][i & 3] = ldg_dev(&out[((size_t)tt * NB + b) * OUTW + u0 * NH + rem]);   \
    }                                                                                    \
  } while (0)

#define SYNC_STORE20(Pr, base)                                                           \
  do {                                                                                   \
    _Pragma("unroll") for (int i = 0; i < 20; i++) {                                     \
      int qq = s * 20 + i;                                                               \
      int tt = (base) + qq / 150;                                                        \
      int rem = qq % 150;                                                                \
      xr[tt & 15][rem] = (_Float16)Pr[i >> 2][i & 3];                                    \
    }                                                                                    \
  } while (0)

  // ---- weights, ONE row per gate lane ----
  h8 Wa0 = zero8(), Wa1 = zero8(), Wa2 = zero8(), Wa3 = zero8(), Wa4 = zero8();
  h8 Wa5 = zero8(), Wa6 = zero8(), Wa7 = zero8(), Wa8 = zero8(), Wa9 = zero8();
  h8 Ua0 = zero8(), Ua1 = zero8(), Ua2 = zero8(), Ua3 = zero8(), Ua4 = zero8();
  h8 Ua5 = zero8(), Ua6 = zero8(), Ua7 = zero8(), Ua8 = zero8(), Ua9 = zero8();
  h8 Ua10 = zero8(), Ua11 = zero8(), Ua12 = zero8(), Ua13 = zero8(), Ua14 = zero8();
  h8 Ua15 = zero8(), Ua16 = zero8(), Ua17 = zero8(), Ua18 = zero8();
  float bhha = 0.f, biha = 0.f;

  if (isgate) {
    const int row = tid;
    const float* wA = (l == 0) ? w_hh0 + (size_t)(d * G3 + row) * NH
                               : w_hh12 + (size_t)(ci * G3 + row) * NH;
    Wa0 = ld8f(wA, 0, NH);  Wa1 = ld8f(wA, 8, NH);  Wa2 = ld8f(wA, 16, NH);
    Wa3 = ld8f(wA, 24, NH); Wa4 = ld8f(wA, 32, NH); Wa5 = ld8f(wA, 40, NH);
    Wa6 = ld8f(wA, 48, NH); Wa7 = ld8f(wA, 56, NH); Wa8 = ld8f(wA, 64, NH);
    Wa9 = ld8f(wA, 72, NH);
    bhha = (l == 0) ? b_hh0[d * G3 + row] : b_hh12[ci * G3 + row];
    if (l > 0) {
      const float* uA = w_ih12 + (size_t)(ci * G3 + row) * (2 * NH);
      Ua0 = ld8f(uA, 0, 150);   Ua1 = ld8f(uA, 8, 150);   Ua2 = ld8f(uA, 16, 150);
      Ua3 = ld8f(uA, 24, 150);  Ua4 = ld8f(uA, 32, 150);  Ua5 = ld8f(uA, 40, 150);
      Ua6 = ld8f(uA, 48, 150);  Ua7 = ld8f(uA, 56, 150);  Ua8 = ld8f(uA, 64, 150);
      Ua9 = ld8f(uA, 72, 150);  Ua10 = ld8f(uA, 80, 150); Ua11 = ld8f(uA, 88, 150);
      Ua12 = ld8f(uA, 96, 150); Ua13 = ld8f(uA, 104, 150); Ua14 = ld8f(uA, 112, 150);
      Ua15 = ld8f(uA, 120, 150); Ua16 = ld8f(uA, 128, 150); Ua17 = ld8f(uA, 136, 150);
      Ua18 = ld8f(uA, 144, 150);
      biha = b_ih12[ci * G3 + row];
    }
  }

  float hreg = 0.f, hh0 = 0.f, hh1 = 0.f, hh2 = 0.f;
  if (ish) {
    hreg = h0[(size_t)(c * NB + b) * NH + hj];
    h16[hj] = (_Float16)hreg;
  }
  if (tid >= 225 && tid < 230) h16[NH + (tid - 225)] = (_Float16)0;
  if (tid < 16) { xr[tid][150] = (_Float16)0; xr[tid][151] = (_Float16)0; }

  // sync-lane double-buffer prefetch regs (const-indexed only)
  f4 PA[5], PB[5];
#pragma unroll
  for (int i = 0; i < 5; i++) { PA[i] = f4{0.f, 0.f, 0.f, 0.f}; PB[i] = f4{0.f, 0.f, 0.f, 0.f}; }

  const int* f0p = (l >= 1) ? &flags[u0 * NB + b] : flags;
  const int* f1p = (l >= 1) ? &flags[(u0 + 1) * NB + b] : flags;
  int fv0 = 0, fv1 = 0;

  // prologue: fill ring times 0..7 directly, preload PB with times 8..11,
  // then pre-verify flag>=16 (covers t=0's PA load of times 12..15).
  if (issync) {
    for (int p = 0; p < 2; p++) {
      while (ldflag(f0p) < 4 * p + 4 || ldflag(f1p) < 4 * p + 4) {}
#pragma unroll
      for (int i = 0; i < 20; i++) {
        int q = s * 20 + i;
        int tt = 4 * p + q / 150;
        int rem = q % 150;
        float v = ldg_dev(&out[((size_t)tt * NB + b) * OUTW + u0 * NH + rem]);
        xr[tt & 15][rem] = (_Float16)v;
      }
    }
    while (ldflag(f0p) < 12 || ldflag(f1p) < 12) {}
    SYNC_LOAD20(PB, 8);
    while (ldflag(f0p) < 16 || ldflag(f1p) < 16) {}
    fv0 = 16; fv1 = 16;
  }

  // prologue: layer-0 gx(0) raw dword (extracted at first consumption)
  const int n0 = d * G3 + tid;  // gx element index for l==0 gate lanes
  float cr = 0.f;
  if (l == 0 && isgate) {
    cr = out[(size_t)b * OUTW + G3 + (n0 >> 1)];
  }
  __syncthreads();  // heavy barrier once, entering steady state

  for (int t = 0; t < LSEQ; t++) {
    // ================= P1 =================
    if (isgate) {
      // keep weights register-resident (defeat remat/reload)
      PIN4(Wa0, Wa1, Wa2, Wa3); PIN4(Wa4, Wa5, Wa6, Wa7); PIN2(Wa8, Wa9);
      if (l > 0) {
        PIN4(Ua0, Ua1, Ua2, Ua3); PIN4(Ua4, Ua5, Ua6, Ua7); PIN4(Ua8, Ua9, Ua10, Ua11);
        PIN4(Ua12, Ua13, Ua14, Ua15); PIN2(Ua16, Ua17); asm("" : "+v"(Ua18));
      }
      const h8* hv = (const h8*)h16;
      h8 H0 = hv[0], H1 = hv[1], H2 = hv[2], H3 = hv[3], H4 = hv[4];
      h8 H5 = hv[5], H6 = hv[6], H7 = hv[7], H8 = hv[8], H9 = hv[9];
      float b0a = dot8(Wa0, H0, bhha), b0b = dot8(Wa1, H1, 0.f);
      b0a = dot8(Wa2, H2, b0a); b0b = dot8(Wa3, H3, b0b);
      b0a = dot8(Wa4, H4, b0a); b0b = dot8(Wa5, H5, b0b);
      b0a = dot8(Wa6, H6, b0a); b0b = dot8(Wa7, H7, b0b);
      b0a = dot8(Wa8, H8, b0a); b0b = dot8(Wa9, H9, b0b);
      float accB = b0a + b0b;
      float accA;
      if (l == 0) {
        // consume gx(t) from the raw dword loaded LAST step (full-step window)
        h2 pc = __builtin_bit_cast(h2, cr);
        accA = (n0 & 1) ? (float)pc[1] : (float)pc[0];
        // then issue the load for gx(t+1) into the same loop-carried reg
        if (t + 1 < LSEQ) {
          cr = out[((size_t)(t + 1) * NB + b) * OUTW + G3 + (n0 >> 1)];
        }
      } else {
        const h8* xv = (const h8*)xr[t & 15];
        h8 X0 = xv[0], X1 = xv[1], X2 = xv[2], X3 = xv[3], X4 = xv[4];
        h8 X5 = xv[5], X6 = xv[6], X7 = xv[7], X8 = xv[8], X9 = xv[9];
        h8 X10 = xv[10], X11 = xv[11], X12 = xv[12], X13 = xv[13], X14 = xv[14];
        h8 X15 = xv[15], X16 = xv[16], X17 = xv[17], X18 = xv[18];
        float a0a = dot8(Ua0, X0, biha), a0b = dot8(Ua1, X1, 0.f);
        a0a = dot8(Ua2, X2, a0a);   a0b = dot8(Ua3, X3, a0b);
        a0a = dot8(Ua4, X4, a0a);   a0b = dot8(Ua5, X5, a0b);
        a0a = dot8(Ua6, X6, a0a);   a0b = dot8(Ua7, X7, a0b);
        a0a = dot8(Ua8, X8, a0a);   a0b = dot8(Ua9, X9, a0b);
        a0a = dot8(Ua10, X10, a0a); a0b = dot8(Ua11, X11, a0b);
        a0a = dot8(Ua12, X12, a0a); a0b = dot8(Ua13, X13, a0b);
        a0a = dot8(Ua14, X14, a0a); a0b = dot8(Ua15, X15, a0b);
        a0a = dot8(Ua16, X16, a0a); a0b = dot8(Ua17, X17, a0b);
        a0a = dot8(Ua18, X18, a0a);
        accA = a0a + a0b;
      }
      A_s[tid] = accA;
      B_s[tid] = accB;
    }
    if (issync && (t & 3) == 0) {
      // (1) retire the 4-step-old prefetch into the ring (times t+8..t+11)
      if (t + 8 < LSEQ) {
        if (t & 4) SYNC_STORE20(PA, t + 8); else SYNC_STORE20(PB, t + 8);
      }
      // (2) flag check for the batch loaded below (times t+16..t+19 needs
      //     flag >= t+20, checked here one batch ahead):
      //     compare the speculatively-loaded values; spin only on miss.
      if (t + 20 <= LSEQ) {
        int need = t + 20;
        if (fv0 < need || fv1 < need) {
          while (ldflag(f0p) < need || ldflag(f1p) < need) {}
        }
      }
      // (3) issue fresh prefetch (times t+12..t+15); consumed at t+4.
      if (t + 12 < LSEQ) {
        if (t & 4) SYNC_LOAD20(PB, t + 12); else SYNC_LOAD20(PA, t + 12);
      }
      // (4) speculative flag reads for the check at t+4 (need = t+24);
      //     waitcnt lands at next check's compare -> full-step in flight.
      if (t + 24 <= LSEQ) {
        fv0 = ldflag(f0p);
        fv1 = ldflag(f1p);
      }
    }
    // publish F = t-4: stores <= t-5 were vmcnt(4)-confirmed at step t-1 P2,
    // and barrier2 of t-1 ordered that before this store.
    if (tid == 0 && c < 4 && (t & 3) == 0 && t >= 8) stflag(&flags[c * NB + b], t - 4);
    WG_BARRIER();  // barrier1 (lgkm-only; vmem stays in flight)

    // ================= P2 =================
    if (ish) {
      float rg = sigm(A_s[hj] + B_s[hj]);
      float zg = sigm(A_s[NH + hj] + B_s[NH + hj]);
      float ng = tanh_f(A_s[2 * NH + hj] + rg * B_s[2 * NH + hj]);
      float hn = (1.f - zg) * ng + zg * hreg;
      hreg = hn;
      h16[hj] = (_Float16)hn;
      hh0 = ((t & 3) == 0) ? hn : hh0;
      hh1 = ((t & 3) == 1) ? hn : hh1;
      hh2 = ((t & 3) == 2) ? hn : hh2;
      if ((t & 3) == 3) {
        float* base = out + (size_t)(t - 3) * NB * OUTW + (size_t)b * OUTW + c * NH + hj;
        stg_dev(base, hh0);
        stg_dev(base + (size_t)NB * OUTW, hh1);
        stg_dev(base + 2 * (size_t)NB * OUTW, hh2);
        stg_dev(base + 3 * (size_t)NB * OUTW, hn);
        // counted drain: all store batches OLDER than these 4 are now
        // globally visible (vmcnt retires in issue order). The gx load of
        // this step was issued ~a full phase earlier -> retired, ~0 stall.
        asm volatile("s_waitcnt vmcnt(4)" ::: "memory");
      }
    }
    WG_BARRIER();  // barrier2 (orders h16/A_s reuse and the vmcnt(4) above)
  }
  __syncthreads();  // full drain (incl. last h-store batch) before final publish
  if (tid == 0 && c < 4) stflag(&flags[c * NB + b], LSEQ);
}

extern "C" void kernel_launch(void* const* d_in, const int* in_sizes, int n_in,
                              void* d_out, int out_size, void* d_ws, size_t ws_size,
                              hipStream_t stream) {
  const float* x      = (const float*)d_in[0];
  const float* h0     = (const float*)d_in[1];
  const float* w_ih0  = (const float*)d_in[2];
  const float* w_hh0  = (const float*)d_in[3];
  const float* b_ih0  = (const float*)d_in[4];
  const float* b_hh0  = (const float*)d_in[5];
  const float* w_ih12 = (const float*)d_in[6];
  const float* w_hh12 = (const float*)d_in[7];
  const float* b_ih12 = (const float*)d_in[8];
  const float* b_hh12 = (const float*)d_in[9];
  float* out = (float*)d_out;
  int* flags = (int*)d_ws;

  hipLaunchKernelGGL(init_flags, dim3(1), dim3(256), 0, stream, flags);
  hipLaunchKernelGGL(gemm_gx, dim3(768), dim3(256), 0, stream, x, w_ih0, b_ih0, out);
  hipLaunchKernelGGL(scan_gru, dim3(144), dim3(256), 0, stream,
                     h0, w_hh0, b_hh0, w_ih12, w_hh12, b_ih12, b_hh12, out, flags);
}

// Round 5
// 2865.646 us; speedup vs baseline: 1.4849x; 1.1144x over previous
//
#include <hip/hip_runtime.h>

#define LSEQ 2048
#define NB 24
#define NH 75
#define G3 225
#define NIN 500
#define OUTW 450

typedef _Float16 h2 __attribute__((ext_vector_type(2)));
typedef _Float16 h8 __attribute__((ext_vector_type(8)));
typedef float f4 __attribute__((ext_vector_type(4)));

__device__ __forceinline__ h2 pkrtz(float a, float b) {
  return __builtin_bit_cast(h2, __builtin_amdgcn_cvt_pkrtz(a, b));
}
__device__ __forceinline__ float dot2(h2 a, h2 b, float c) {
  return __builtin_amdgcn_fdot2(a, b, c, false);
}
// 8-wide half dot: pairs align to dwords, so extracts are free sub-reg refs
__device__ __forceinline__ float dot8(h8 w, h8 x, float c) {
  h2 w0{w[0], w[1]}, w1{w[2], w[3]}, w2{w[4], w[5]}, w3{w[6], w[7]};
  h2 x0{x[0], x[1]}, x1{x[2], x[3]}, x2{x[4], x[5]}, x3{x[6], x[7]};
  c = dot2(w0, x0, c);
  c = dot2(w1, x1, c);
  c = dot2(w2, x2, c);
  c = dot2(w3, x3, c);
  return c;
}
__device__ __forceinline__ h8 ld8f(const float* p, int base, int n) {
  h8 o;
#pragma unroll
  for (int i = 0; i < 8; i += 2) {
    float a = (base + i < n) ? p[base + i] : 0.f;
    float b = (base + i + 1 < n) ? p[base + i + 1] : 0.f;
    h2 t = pkrtz(a, b);
    o[i] = t[0];
    o[i + 1] = t[1];
  }
  return o;
}
__device__ __forceinline__ h8 zero8() {
  h8 v;
#pragma unroll
  for (int i = 0; i < 8; i++) v[i] = (_Float16)0;
  return v;
}
__device__ __forceinline__ float sigm(float x) {
  return __builtin_amdgcn_rcpf(1.f + __builtin_amdgcn_exp2f(-1.4426950408889634f * x));
}
__device__ __forceinline__ float tanh_f(float x) {
  float xx = fminf(x, 15.f);
  float e = __builtin_amdgcn_exp2f(2.8853900817779268f * xx);
  return (e - 1.f) * __builtin_amdgcn_rcpf(e + 1.f);
}

// device-scope relaxed (sc1, no cache-maintenance ops)
__device__ __forceinline__ float ldg_dev(const float* p) {
  return __hip_atomic_load(p, __ATOMIC_RELAXED, __HIP_MEMORY_SCOPE_AGENT);
}
__device__ __forceinline__ void stg_dev(float* p, float v) {
  __hip_atomic_store(p, v, __ATOMIC_RELAXED, __HIP_MEMORY_SCOPE_AGENT);
}
__device__ __forceinline__ int ldflag(const int* p) {
  return __hip_atomic_load(p, __ATOMIC_RELAXED, __HIP_MEMORY_SCOPE_AGENT);
}
__device__ __forceinline__ void stflag(int* p, int v) {
  __hip_atomic_store(p, v, __ATOMIC_RELAXED, __HIP_MEMORY_SCOPE_AGENT);
}

#define PIN4(a, b, c, d) asm("" : "+v"(a), "+v"(b), "+v"(c), "+v"(d))
#define PIN2(a, b) asm("" : "+v"(a), "+v"(b))

// Raw workgroup barrier: does NOT drain vmcnt.
// LDS producer->consumer ordering needs lgkmcnt(0) on the writer side;
// sched_barrier(0) pins the instruction scheduler on both sides (rule #18).
#define WG_BARRIER()                                     \
  do {                                                   \
    asm volatile("s_waitcnt lgkmcnt(0)" ::: "memory");   \
    __builtin_amdgcn_sched_barrier(0);                   \
    __builtin_amdgcn_s_barrier();                        \
    __builtin_amdgcn_sched_barrier(0);                   \
  } while (0)

// ---------------- init flags ----------------
__global__ void init_flags(int* f) {
  if (threadIdx.x < 144) stflag(&f[threadIdx.x], 0);
}

// ---------------- kernel A: gx GEMM (unchanged, it works) ----------------
__device__ __forceinline__ void load8_guard(float* v, const float* src, int kbase, bool rowvalid) {
  if (rowvalid && (kbase + 8 <= NIN)) {
    f4 t0 = *(const f4*)(src);
    f4 t1 = *(const f4*)(src + 4);
    v[0] = t0[0]; v[1] = t0[1]; v[2] = t0[2]; v[3] = t0[3];
    v[4] = t1[0]; v[5] = t1[1]; v[6] = t1[2]; v[7] = t1[3];
  } else {
#pragma unroll
    for (int i = 0; i < 8; i++) v[i] = (rowvalid && (kbase + i < NIN)) ? src[i] : 0.f;
  }
}
__device__ __forceinline__ void pack8_store(_Float16* dst, const float* v) {
  h2 a = pkrtz(v[0], v[1]);
  h2 b = pkrtz(v[2], v[3]);
  h2 c = pkrtz(v[4], v[5]);
  h2 d = pkrtz(v[6], v[7]);
  h8 o;
  o[0] = a[0]; o[1] = a[1]; o[2] = b[0]; o[3] = b[1];
  o[4] = c[0]; o[5] = c[1]; o[6] = d[0]; o[7] = d[1];
  *(h8*)dst = o;
}

__global__ __launch_bounds__(256) void gemm_gx(const float* __restrict__ x,
                                               const float* __restrict__ w,
                                               const float* __restrict__ bias,
                                               float* __restrict__ out) {
  __shared__ __align__(16) _Float16 xs[64 * 40];
  __shared__ __align__(16) _Float16 wsh[464 * 40];
  const int tid = threadIdx.x;
  const int blk = blockIdx.x;
  const int lane = tid & 63, wid = tid >> 6;
  const int q = lane >> 4, cn = lane & 15;
  const int r = tid >> 2, kq = tid & 3;

  f4 acc[29];
#pragma unroll
  for (int j = 0; j < 29; j++) acc[j] = f4{0.f, 0.f, 0.f, 0.f};

  for (int kc = 0; kc < 16; kc++) {
    const int kbase = kc * 32 + kq * 8;
    {
      const float* src = x + (size_t)(blk * 64 + r) * NIN + kbase;
      float v[8];
      load8_guard(v, src, kbase, true);
      pack8_store(&xs[r * 40 + kq * 8], v);
    }
#pragma unroll
    for (int it = 0; it < 8; it++) {
      int rr = r + it * 64;
      if (rr < 464) {
        const float* src = w + (size_t)rr * NIN + kbase;
        float v[8];
        load8_guard(v, src, kbase, rr < OUTW);
        pack8_store(&wsh[rr * 40 + kq * 8], v);
      }
    }
    __syncthreads();
    h8 a = *(const h8*)&xs[(wid * 16 + cn) * 40 + q * 8];
#pragma unroll
    for (int j = 0; j < 29; j++) {
      h8 bf = *(const h8*)&wsh[(j * 16 + cn) * 40 + q * 8];
      acc[j] = __builtin_amdgcn_mfma_f32_16x16x32_f16(a, bf, acc[j], 0, 0, 0);
    }
    __syncthreads();
  }
#pragma unroll
  for (int j = 0; j < 29; j++) {
    int n = j * 16 + cn;
    float bv = (n < OUTW) ? bias[n] : 0.f;
#pragma unroll
    for (int rr = 0; rr < 4; rr++) {
      float val = acc[j][rr] + bv;
      float partner = __shfl_xor(val, 1, 64);
      if (((lane & 1) == 0) && n < OUTW) {
        h2 pk = pkrtz(val, partner);
        int mg = blk * 64 + wid * 16 + q * 4 + rr;
        out[(size_t)mg * OUTW + G3 + (n >> 1)] = __builtin_bit_cast(float, pk);
      }
    }
  }
}

// ---------------- kernel B: persistent GRU scan ----------------
// 144 WGs = cell c (0..5) x batch b (0..23), bi = c*24+b.
// Lane map: tid 0..224 gate lanes, ONE row each (row = tid);
//   h-update lanes = tid 0..74 (hj = tid); sync lanes tid 225..254.
// R5: U.x SOFTWARE-PIPELINED OFF THE SERIAL PATH.
//   The a-dots (U.x, 19 dot8 + 19 b128 reads, the longest dependent chain)
//   do not depend on h(t): compute xa = a-dots(t+1) in P2(t) (150/225 gate
//   lanes idle there; h-lanes interleave with latency-bound activations),
//   carry in a register, and P1(t) just stores A_s[tid]=xa FIRST (store
//   latency hidden under the W-dots) then runs only the W.h chain.
//   Accumulation order inside A_DOTS is unchanged -> bitwise-identical.
// Sync scheme unchanged from R4 (raw barriers, PA/PB prefetch, speculative
// flags, vmcnt(4) producer drain, flag lag 4).
__global__ __launch_bounds__(256, 1) __attribute__((amdgpu_waves_per_eu(1)))
void scan_gru(const float* __restrict__ h0,
              const float* __restrict__ w_hh0, const float* __restrict__ b_hh0,
              const float* __restrict__ w_ih12, const float* __restrict__ w_hh12,
              const float* __restrict__ b_ih12, const float* __restrict__ b_hh12,
              float* __restrict__ out, int* flags) {
  __shared__ __align__(16) float A_s[232], B_s[232];
  __shared__ __align__(16) _Float16 h16[80];
  __shared__ __align__(16) _Float16 xr[16][152];

  const int bi = blockIdx.x;
  if (bi >= 144) return;
  const int tid = threadIdx.x;
  const int c = bi / NB, b = bi % NB;
  const int l = c >> 1, d = c & 1;
  const int ci = (l - 1) * 2 + d;   // index into *_12 arrays (l>=1)
  const int u0 = (l - 1) * 2;       // upstream cell pair

  const bool isgate = (tid < G3);   // one row per lane: row = tid
  const bool ish = (tid < NH);      // hj = tid
  const int hj = tid;
  const int s = tid - 225;
  const bool issync = (s >= 0) && (s < 30) && (l >= 1);

#define SYNC_LOAD20(Pr, base)                                                            \
  do {                                                                                   \
    _Pragma("unroll") for (int i = 0; i < 20; i++) {                                     \
      int qq = s * 20 + i;                                                               \
      int tt = (base) + qq / 150;                                                        \
      int rem = qq % 150;                                                                \
      Pr[i >> 2][i & 3] = ldg_dev(&out[((size_t)tt * NB + b) * OUTW + u0 * NH + rem]);   \
    }                                                                                    \
  } while (0)

#define SYNC_STORE20(Pr, base)                                                           \
  do {                                                                                   \
    _Pragma("unroll") for (int i = 0; i < 20; i++) {                                     \
      int qq = s * 20 + i;                                                               \
      int tt = (base) + qq / 150;                                                        \
      int rem = qq % 150;                                                                \
      xr[tt & 15][rem] = (_Float16)Pr[i >> 2][i & 3];                                    \
    }                                                                                    \
  } while (0)

  // ---- weights, ONE row per gate lane ----
  h8 Wa0 = zero8(), Wa1 = zero8(), Wa2 = zero8(), Wa3 = zero8(), Wa4 = zero8();
  h8 Wa5 = zero8(), Wa6 = zero8(), Wa7 = zero8(), Wa8 = zero8(), Wa9 = zero8();
  h8 Ua0 = zero8(), Ua1 = zero8(), Ua2 = zero8(), Ua3 = zero8(), Ua4 = zero8();
  h8 Ua5 = zero8(), Ua6 = zero8(), Ua7 = zero8(), Ua8 = zero8(), Ua9 = zero8();
  h8 Ua10 = zero8(), Ua11 = zero8(), Ua12 = zero8(), Ua13 = zero8(), Ua14 = zero8();
  h8 Ua15 = zero8(), Ua16 = zero8(), Ua17 = zero8(), Ua18 = zero8();
  float bhha = 0.f, biha = 0.f;

  // a-dot chain for x(t+1): SAME accumulation order as the original in-P1
  // version (a0a/a0b split, same operand sequence) -> identical rounding.
#define A_DOTS(dst, slot)                                                     \
  do {                                                                        \
    const h8* xv = (const h8*)xr[slot];                                       \
    h8 X0 = xv[0], X1 = xv[1], X2 = xv[2], X3 = xv[3], X4 = xv[4];            \
    h8 X5 = xv[5], X6 = xv[6], X7 = xv[7], X8 = xv[8], X9 = xv[9];            \
    h8 X10 = xv[10], X11 = xv[11], X12 = xv[12], X13 = xv[13], X14 = xv[14];  \
    h8 X15 = xv[15], X16 = xv[16], X17 = xv[17], X18 = xv[18];                \
    float a0a = dot8(Ua0, X0, biha), a0b = dot8(Ua1, X1, 0.f);                \
    a0a = dot8(Ua2, X2, a0a);   a0b = dot8(Ua3, X3, a0b);                     \
    a0a = dot8(Ua4, X4, a0a);   a0b = dot8(Ua5, X5, a0b);                     \
    a0a = dot8(Ua6, X6, a0a);   a0b = dot8(Ua7, X7, a0b);                     \
    a0a = dot8(Ua8, X8, a0a);   a0b = dot8(Ua9, X9, a0b);                     \
    a0a = dot8(Ua10, X10, a0a); a0b = dot8(Ua11, X11, a0b);                   \
    a0a = dot8(Ua12, X12, a0a); a0b = dot8(Ua13, X13, a0b);                   \
    a0a = dot8(Ua14, X14, a0a); a0b = dot8(Ua15, X15, a0b);                   \
    a0a = dot8(Ua16, X16, a0a); a0b = dot8(Ua17, X17, a0b);                   \
    a0a = dot8(Ua18, X18, a0a);                                               \
    dst = a0a + a0b;                                                          \
  } while (0)

  if (isgate) {
    const int row = tid;
    const float* wA = (l == 0) ? w_hh0 + (size_t)(d * G3 + row) * NH
                               : w_hh12 + (size_t)(ci * G3 + row) * NH;
    Wa0 = ld8f(wA, 0, NH);  Wa1 = ld8f(wA, 8, NH);  Wa2 = ld8f(wA, 16, NH);
    Wa3 = ld8f(wA, 24, NH); Wa4 = ld8f(wA, 32, NH); Wa5 = ld8f(wA, 40, NH);
    Wa6 = ld8f(wA, 48, NH); Wa7 = ld8f(wA, 56, NH); Wa8 = ld8f(wA, 64, NH);
    Wa9 = ld8f(wA, 72, NH);
    bhha = (l == 0) ? b_hh0[d * G3 + row] : b_hh12[ci * G3 + row];
    if (l > 0) {
      const float* uA = w_ih12 + (size_t)(ci * G3 + row) * (2 * NH);
      Ua0 = ld8f(uA, 0, 150);   Ua1 = ld8f(uA, 8, 150);   Ua2 = ld8f(uA, 16, 150);
      Ua3 = ld8f(uA, 24, 150);  Ua4 = ld8f(uA, 32, 150);  Ua5 = ld8f(uA, 40, 150);
      Ua6 = ld8f(uA, 48, 150);  Ua7 = ld8f(uA, 56, 150);  Ua8 = ld8f(uA, 64, 150);
      Ua9 = ld8f(uA, 72, 150);  Ua10 = ld8f(uA, 80, 150); Ua11 = ld8f(uA, 88, 150);
      Ua12 = ld8f(uA, 96, 150); Ua13 = ld8f(uA, 104, 150); Ua14 = ld8f(uA, 112, 150);
      Ua15 = ld8f(uA, 120, 150); Ua16 = ld8f(uA, 128, 150); Ua17 = ld8f(uA, 136, 150);
      Ua18 = ld8f(uA, 144, 150);
      biha = b_ih12[ci * G3 + row];
    }
  }

  float hreg = 0.f, hh0 = 0.f, hh1 = 0.f, hh2 = 0.f;
  if (ish) {
    hreg = h0[(size_t)(c * NB + b) * NH + hj];
    h16[hj] = (_Float16)hreg;
  }
  if (tid >= 225 && tid < 230) h16[NH + (tid - 225)] = (_Float16)0;
  if (tid < 16) { xr[tid][150] = (_Float16)0; xr[tid][151] = (_Float16)0; }

  // sync-lane double-buffer prefetch regs (const-indexed only)
  f4 PA[5], PB[5];
#pragma unroll
  for (int i = 0; i < 5; i++) { PA[i] = f4{0.f, 0.f, 0.f, 0.f}; PB[i] = f4{0.f, 0.f, 0.f, 0.f}; }

  const int* f0p = (l >= 1) ? &flags[u0 * NB + b] : flags;
  const int* f1p = (l >= 1) ? &flags[(u0 + 1) * NB + b] : flags;
  int fv0 = 0, fv1 = 0;

  // prologue: fill ring times 0..7 directly, preload PB with times 8..11,
  // then pre-verify flag>=16 (covers t=0's PA load of times 12..15).
  if (issync) {
    for (int p = 0; p < 2; p++) {
      while (ldflag(f0p) < 4 * p + 4 || ldflag(f1p) < 4 * p + 4) {}
#pragma unroll
      for (int i = 0; i < 20; i++) {
        int q = s * 20 + i;
        int tt = 4 * p + q / 150;
        int rem = q % 150;
        float v = ldg_dev(&out[((size_t)tt * NB + b) * OUTW + u0 * NH + rem]);
        xr[tt & 15][rem] = (_Float16)v;
      }
    }
    while (ldflag(f0p) < 12 || ldflag(f1p) < 12) {}
    SYNC_LOAD20(PB, 8);
    while (ldflag(f0p) < 16 || ldflag(f1p) < 16) {}
    fv0 = 16; fv1 = 16;
  }

  // prologue: layer-0 gx(0) raw dword (extracted at first consumption)
  const int n0 = d * G3 + tid;  // gx element index for l==0 gate lanes
  float cr = 0.f;
  if (l == 0 && isgate) {
    cr = out[(size_t)b * OUTW + G3 + (n0 >> 1)];
  }
  __syncthreads();  // ring slots 0..7 now visible to all lanes

  // prologue: xa(0) = U.x(0) from ring slot 0 (l>=1 gate lanes)
  float xa = 0.f;
  if (l > 0 && isgate) {
    A_DOTS(xa, 0);
  }

  for (int t = 0; t < LSEQ; t++) {
    // ================= P1 =================
    if (isgate) {
      // x-part is precomputed (xa): store it FIRST so the A_s write latency
      // hides under the W-dots that follow.
      if (l > 0) A_s[tid] = xa;
      // keep W weights register-resident (defeat remat/reload)
      PIN4(Wa0, Wa1, Wa2, Wa3); PIN4(Wa4, Wa5, Wa6, Wa7); PIN2(Wa8, Wa9);
      const h8* hv = (const h8*)h16;
      h8 H0 = hv[0], H1 = hv[1], H2 = hv[2], H3 = hv[3], H4 = hv[4];
      h8 H5 = hv[5], H6 = hv[6], H7 = hv[7], H8 = hv[8], H9 = hv[9];
      float b0a = dot8(Wa0, H0, bhha), b0b = dot8(Wa1, H1, 0.f);
      b0a = dot8(Wa2, H2, b0a); b0b = dot8(Wa3, H3, b0b);
      b0a = dot8(Wa4, H4, b0a); b0b = dot8(Wa5, H5, b0b);
      b0a = dot8(Wa6, H6, b0a); b0b = dot8(Wa7, H7, b0b);
      b0a = dot8(Wa8, H8, b0a); b0b = dot8(Wa9, H9, b0b);
      float accB = b0a + b0b;
      if (l == 0) {
        // consume gx(t) from the raw dword loaded LAST step (full-step window)
        h2 pc = __builtin_bit_cast(h2, cr);
        float accA = (n0 & 1) ? (float)pc[1] : (float)pc[0];
        A_s[tid] = accA;
        // then issue the load for gx(t+1) into the same loop-carried reg
        if (t + 1 < LSEQ) {
          cr = out[((size_t)(t + 1) * NB + b) * OUTW + G3 + (n0 >> 1)];
        }
      }
      B_s[tid] = accB;
    }
    if (issync && (t & 3) == 0) {
      // (1) retire the 4-step-old prefetch into the ring (times t+8..t+11)
      if (t + 8 < LSEQ) {
        if (t & 4) SYNC_STORE20(PA, t + 8); else SYNC_STORE20(PB, t + 8);
      }
      // (2) flag check for the batch loaded below (times t+16..t+19 needs
      //     flag >= t+20): compare speculative values; spin only on miss.
      if (t + 20 <= LSEQ) {
        int need = t + 20;
        if (fv0 < need || fv1 < need) {
          while (ldflag(f0p) < need || ldflag(f1p) < need) {}
        }
      }
      // (3) issue fresh prefetch (times t+12..t+15); consumed at t+4.
      if (t + 12 < LSEQ) {
        if (t & 4) SYNC_LOAD20(PB, t + 12); else SYNC_LOAD20(PA, t + 12);
      }
      // (4) speculative flag reads for the check at t+4 (need = t+24).
      if (t + 24 <= LSEQ) {
        fv0 = ldflag(f0p);
        fv1 = ldflag(f1p);
      }
    }
    // publish F = t-4: stores <= t-5 were vmcnt(4)-confirmed at step t-1 P2,
    // and barrier2 of t-1 ordered that before this store.
    if (tid == 0 && c < 4 && (t & 3) == 0 && t >= 8) stflag(&flags[c * NB + b], t - 4);
    WG_BARRIER();  // barrier1 (lgkm-only; vmem stays in flight)

    // ================= P2 =================
    if (ish) {
      float rg = sigm(A_s[hj] + B_s[hj]);
      float zg = sigm(A_s[NH + hj] + B_s[NH + hj]);
      float ng = tanh_f(A_s[2 * NH + hj] + rg * B_s[2 * NH + hj]);
      float hn = (1.f - zg) * ng + zg * hreg;
      hreg = hn;
      h16[hj] = (_Float16)hn;
      hh0 = ((t & 3) == 0) ? hn : hh0;
      hh1 = ((t & 3) == 1) ? hn : hh1;
      hh2 = ((t & 3) == 2) ? hn : hh2;
      if ((t & 3) == 3) {
        float* base = out + (size_t)(t - 3) * NB * OUTW + (size_t)b * OUTW + c * NH + hj;
        stg_dev(base, hh0);
        stg_dev(base + (size_t)NB * OUTW, hh1);
        stg_dev(base + 2 * (size_t)NB * OUTW, hh2);
        stg_dev(base + 3 * (size_t)NB * OUTW, hn);
        // counted drain: all store batches OLDER than these 4 are now
        // globally visible (vmcnt retires in issue order). ~0 actual wait.
        asm volatile("s_waitcnt vmcnt(4)" ::: "memory");
      }
    }
    // a-dots for step t+1, OFF the serial path: x(t+1) is ring-resident
    // (slot (t+1)&15; sync stores this step touch slots (t+8..t+11)&15 —
    // disjoint). 150/225 gate lanes were idle here; h-lanes interleave
    // these issue-heavy dots with their latency-bound activation chain.
    if (l > 0 && isgate && (t + 1 < LSEQ)) {
      PIN4(Ua0, Ua1, Ua2, Ua3); PIN4(Ua4, Ua5, Ua6, Ua7); PIN4(Ua8, Ua9, Ua10, Ua11);
      PIN4(Ua12, Ua13, Ua14, Ua15); PIN2(Ua16, Ua17); asm("" : "+v"(Ua18));
      A_DOTS(xa, (t + 1) & 15);
    }
    WG_BARRIER();  // barrier2 (orders h16/A_s reuse and the vmcnt(4) above)
  }
  __syncthreads();  // full drain (incl. last h-store batch) before final publish
  if (tid == 0 && c < 4) stflag(&flags[c * NB + b], LSEQ);
}

extern "C" void kernel_launch(void* const* d_in, const int* in_sizes, int n_in,
                              void* d_out, int out_size, void* d_ws, size_t ws_size,
                              hipStream_t stream) {
  const float* x      = (const float*)d_in[0];
  const float* h0     = (const float*)d_in[1];
  const float* w_ih0  = (const float*)d_in[2];
  const float* w_hh0  = (const float*)d_in[3];
  const float* b_ih0  = (const float*)d_in[4];
  const float* b_hh0  = (const float*)d_in[5];
  const float* w_ih12 = (const float*)d_in[6];
  const float* w_hh12 = (const float*)d_in[7];
  const float* b_ih12 = (const float*)d_in[8];
  const float* b_hh12 = (const float*)d_in[9];
  float* out = (float*)d_out;
  int* flags = (int*)d_ws;

  hipLaunchKernelGGL(init_flags, dim3(1), dim3(256), 0, stream, flags);
  hipLaunchKernelGGL(gemm_gx, dim3(768), dim3(256), 0, stream, x, w_ih0, b_ih0, out);
  hipLaunchKernelGGL(scan_gru, dim3(144), dim3(256), 0, stream,
                     h0, w_hh0, b_hh0, w_ih12, w_hh12, b_ih12, b_hh12, out, flags);
}